// Round 1
// 499.736 us; speedup vs baseline: 1.1363x; 1.1363x over previous
//
#include <hip/hip_runtime.h>

typedef unsigned short u16;
typedef __attribute__((ext_vector_type(8))) short short8;   // 8 bf16 = 4 VGPRs (MFMA A/B frag)
typedef __attribute__((ext_vector_type(4))) float f32x4;    // MFMA C/D frag

#define T_SEQ 4096
#define DMODEL 1024
#define NH 16
#define DKH 64
#define KPROJ 256

// ---------- bf16 helpers (bit-level, RNE) ----------
__device__ __forceinline__ u16 f2bf(float f) {
  union { float f; unsigned u; } v; v.f = f;
  unsigned r = v.u + 0x7FFFu + ((v.u >> 16) & 1u);
  return (u16)(r >> 16);
}
__device__ __forceinline__ float bf2f(u16 h) {
  union { unsigned u; float f; } v; v.u = ((unsigned)h) << 16; return v.f;
}

// ---------- async global->LDS, 16B/lane; LDS base wave-uniform, lane i lands at +16*i ----------
__device__ __forceinline__ void gl2lds16(const u16* g, u16* l) {
  __builtin_amdgcn_global_load_lds(
      (const __attribute__((address_space(1))) unsigned int*)g,
      (__attribute__((address_space(3))) unsigned int*)(unsigned int)(unsigned long long)l,
      16, 0, 0);
}

// ---------- dtype sniffer: fp32 read as u16 pairs -> ~0.4% NaN/Inf bf16 patterns ----------
__global__ void sniff_dtype(const u16* __restrict__ x, int* __restrict__ flag) {
  int c = 0;
  for (int i = threadIdx.x; i < 8192; i += 64)
    if ((x[2 * i] & 0x7F80) == 0x7F80) c++;
#pragma unroll
  for (int m = 1; m < 64; m <<= 1) c += __shfl_xor(c, m);
  if (threadIdx.x == 0) *flag = (c > 0) ? 1 : 0;   // 1 = inputs are float32
}

// ---------- x -> bf16 row-major copy/downconvert ----------
__global__ void convert_x(const void* __restrict__ xin, u16* __restrict__ xout,
                          const int* __restrict__ flag, int n) {
  const int i = (blockIdx.x * 256 + threadIdx.x) * 8;
  if (i >= n) return;
  if (*flag) {
    const float* f = (const float*)xin + i;
    union { u16 s[8]; short8 v; } o;
#pragma unroll
    for (int j = 0; j < 8; ++j) o.s[j] = f2bf(f[j]);
    *(short8*)(xout + i) = o.v;
  } else {
    *(short8*)(xout + i) = *(const short8*)((const u16*)xin + i);
  }
}

// ---------- batched tiled transpose+convert: out[z][c][r] = bf16(in[z][r][c]) ----------
__global__ void transpose_cvt(const void* __restrict__ in, u16* __restrict__ out,
                              int R, int C, const int* __restrict__ flag) {
  __shared__ u16 tile[32][33];
  const bool f32 = (*flag != 0);
  const size_t zoff = (size_t)blockIdx.z * R * C;
  const int c0 = blockIdx.x * 32, r0 = blockIdx.y * 32;
  for (int i = threadIdx.y; i < 32; i += 8) {
    const size_t idx = zoff + (size_t)(r0 + i) * C + c0 + threadIdx.x;
    tile[i][threadIdx.x] = f32 ? f2bf(((const float*)in)[idx]) : ((const u16*)in)[idx];
  }
  __syncthreads();
  for (int i = threadIdx.y; i < 32; i += 8)
    out[zoff + (size_t)(c0 + i) * R + r0 + threadIdx.x] = tile[threadIdx.x][i];
}

// ---------- split-K reduce: xE[b][j] = bf16(sum_s P[(b*4+s)*stride + j]) ----------
__global__ void reduce_splitk(const float* __restrict__ P, u16* __restrict__ out) {
  const int b = blockIdx.y;
  const int j = (blockIdx.x * 256 + threadIdx.x) * 8;
  const float* p = P + (size_t)b * 4 * 524288 + j;
  float acc[8] = {};
#pragma unroll
  for (int s = 0; s < 4; ++s) {
    const float4 v0 = *(const float4*)(p + (size_t)s * 524288);
    const float4 v1 = *(const float4*)(p + (size_t)s * 524288 + 4);
    acc[0] += v0.x; acc[1] += v0.y; acc[2] += v0.z; acc[3] += v0.w;
    acc[4] += v1.x; acc[5] += v1.y; acc[6] += v1.z; acc[7] += v1.w;
  }
  union { u16 s[8]; short8 v; } o;
#pragma unroll
  for (int k = 0; k < 8; ++k) o.s[k] = f2bf(acc[k]);
  *(short8*)(out + (size_t)b * 524288 + j) = o.v;
}

// ---------- batched C = A(MxK') @ Bt(NxK')^T, 128x128 tile, BK=32, 4 waves ----------
// 2-phase double-buffered prefetch: stage tile t+1 into LDS buf^1 while computing
// tile t from buf (one barrier/iter; __syncthreads drains vmcnt so t+1 is ready).
// XCD-aware bijective linear-block swizzle (all grids %8==0): same-A-panel blocks
// land on one XCD's L2 instead of 8.
// MODE 0: bf16 C; batch strides sA/sB/sC, ldA=ldB=K.
// MODE 1: + bias[n]; out dtype fp32/bf16 per *flag.
// MODE 2: split-K fp32 partials: z = b*4+s; kstart = s*K; P block z of M*N floats.
template <int MODE>
__global__ void __launch_bounds__(256) gemm_bt(const u16* __restrict__ A0, const u16* __restrict__ Bt0,
                                               const void* __restrict__ bias, void* __restrict__ Cv,
                                               const int* __restrict__ flag, int M, int N, int K,
                                               int ldA, int ldB, size_t sA, size_t sB, size_t sC) {
  __shared__ __align__(16) u16 As[2][128 * 32];
  __shared__ __align__(16) u16 Bs[2][128 * 32];

  // XCD swizzle: consecutive linear block IDs round-robin across the 8 XCDs.
  // Remap so each XCD owns a contiguous chunk of tile space (A-panel L2 reuse).
  const int gx = gridDim.x, gy = gridDim.y;
  const int gxy = gx * gy;
  const int nwg = gxy * gridDim.z;
  int lin = (blockIdx.z * gy + blockIdx.y) * gx + blockIdx.x;
  if ((nwg & 7) == 0) lin = (lin & 7) * (nwg >> 3) + (lin >> 3);
  const int bz = lin / gxy;
  const int rem = lin - bz * gxy;
  const int by = rem / gx;
  const int bx = rem - by * gx;

  const int z = bz;
  const int bb = (MODE == 2) ? (z >> 2) : z;
  const int kstart = (MODE == 2) ? ((z & 3) * K) : 0;
  const u16* A = A0 + (size_t)bb * sA;
  const u16* Bt = Bt0 + (size_t)bb * sB;
  const int tid = threadIdx.x;
  const int wid = tid >> 6, lane = tid & 63;
  const int wm = wid >> 1, wn = wid & 1;
  const int quad = lane >> 4, l16 = lane & 15;
  const int m0 = by * 128, n0 = bx * 128;
  const int srow = lane >> 2, scol = (lane & 3) * 8;

  const u16* Ag = A + (size_t)(m0 + srow) * ldA + scol + kstart;
  const u16* Bg = Bt + (size_t)(n0 + srow) * ldB + scol + kstart;

  f32x4 acc[4][4] = {};

  auto stage = [&](int buf, int k0) {
#pragma unroll
    for (int r = 0; r < 2; ++r) {
      const int rowb = r * 64 + wid * 16;               // wave-uniform LDS base
      gl2lds16(Ag + (size_t)rowb * ldA + k0, &As[buf][rowb * 32]);
      gl2lds16(Bg + (size_t)rowb * ldB + k0, &Bs[buf][rowb * 32]);
    }
  };

  const int nI = K >> 5;
  stage(0, 0);
  __syncthreads();
  int cur = 0;

  for (int t = 0; t < nI; ++t) {
    if (t + 1 < nI) stage(cur ^ 1, (t + 1) << 5);       // prefetch next tile
    short8 a[4], b[4];
#pragma unroll
    for (int mi = 0; mi < 4; ++mi)
      a[mi] = *(const short8*)(&As[cur][(wm * 64 + mi * 16 + l16) * 32 + quad * 8]);
#pragma unroll
    for (int ni = 0; ni < 4; ++ni)
      b[ni] = *(const short8*)(&Bs[cur][(wn * 64 + ni * 16 + l16) * 32 + quad * 8]);
#pragma unroll
    for (int mi = 0; mi < 4; ++mi)
#pragma unroll
      for (int ni = 0; ni < 4; ++ni)
        acc[mi][ni] = __builtin_amdgcn_mfma_f32_16x16x32_bf16(a[mi], b[ni], acc[mi][ni], 0, 0, 0);
    __syncthreads();                                    // drains vmcnt -> next buf ready
    cur ^= 1;
  }

  const bool f32out = (MODE == 1) && (*flag != 0);
  float* Pz = (MODE == 2) ? ((float*)Cv + (size_t)z * M * N) : nullptr;
#pragma unroll
  for (int mi = 0; mi < 4; ++mi) {
#pragma unroll
    for (int ni = 0; ni < 4; ++ni) {
      const int mloc = wm * 64 + mi * 16 + quad * 4;
      const int n = n0 + wn * 64 + ni * 16 + l16;
      float badd = 0.0f;
      if (MODE == 1)
        badd = f32out ? ((const float*)bias)[n] : bf2f(((const u16*)bias)[n]);
#pragma unroll
      for (int r = 0; r < 4; ++r) {
        if (MODE == 2) {
          Pz[(size_t)(m0 + mloc + r) * N + n] = acc[mi][ni][r];
        } else {
          const size_t oi = (size_t)bb * sC + (size_t)(m0 + mloc + r) * N + n;
          if (f32out) ((float*)Cv)[oi] = acc[mi][ni][r] + badd;
          else        ((u16*)Cv)[oi]  = f2bf(acc[mi][ni][r] + badd);
        }
      }
    }
  }
}

// ---------- fused scores+softmax+ctx ----------
// grid (T/64, B*H), 128 threads (2 waves), 32 Q-rows per wave (2 m-tiles of 16).
// Kp[b]: (256 x 1024) row-major, head slice cols h*64..; Vp^T[b]: (1024 x 256), rows h*64+d.
// Ps wave-private (no barrier); 1/sum folded into ctx epilogue (same C-layout row mapping).
__global__ void __launch_bounds__(128, 2) attn_fused(const u16* Q, const u16* __restrict__ Kp,
                                                     const u16* __restrict__ VpT, u16* Ctx) {
  __shared__ __align__(16) u16 Ps[2 * 32 * 264];
  const int bh = blockIdx.y, b = bh >> 4, h = bh & 15;
  const int t0 = blockIdx.x * 64;
  const int tid = threadIdx.x, wid = tid >> 6, lane = tid & 63;
  const int quad = lane >> 4, l16 = lane & 15;
  const int row0 = wid * 32;
  const u16* Qb = Q + ((size_t)b * T_SEQ + t0 + row0) * DMODEL + h * DKH;
  const u16* Kpb = Kp + (size_t)b * (KPROJ * DMODEL) + h * DKH;
  const u16* Vpb = VpT + (size_t)b * (DMODEL * KPROJ) + (size_t)(h * DKH) * KPROJ;
  u16* PsW = Ps + wid * (32 * 264);

  f32x4 s0[16] = {}, s1[16] = {};
#pragma unroll
  for (int kk = 0; kk < 2; ++kk) {
    short8 bfr[16];
#pragma unroll
    for (int ni = 0; ni < 16; ++ni)
      bfr[ni] = *(const short8*)(Kpb + (size_t)(ni * 16 + l16) * DMODEL + kk * 32 + quad * 8);
    short8 a0 = *(const short8*)(Qb + (size_t)l16 * DMODEL + kk * 32 + quad * 8);
    short8 a1 = *(const short8*)(Qb + (size_t)(16 + l16) * DMODEL + kk * 32 + quad * 8);
#pragma unroll
    for (int ni = 0; ni < 16; ++ni) {
      s0[ni] = __builtin_amdgcn_mfma_f32_16x16x32_bf16(a0, bfr[ni], s0[ni], 0, 0, 0);
      s1[ni] = __builtin_amdgcn_mfma_f32_16x16x32_bf16(a1, bfr[ni], s1[ni], 0, 0, 0);
    }
  }

  const float sc = 0.125f * 1.44269504f;   // 1/sqrt(64) * log2(e)
  float inv[2][4];
#pragma unroll
  for (int mt = 0; mt < 2; ++mt) {
    f32x4* s = mt ? s1 : s0;
#pragma unroll
    for (int r = 0; r < 4; ++r) {
      float mx = -3.0e38f;
#pragma unroll
      for (int ni = 0; ni < 16; ++ni) {
        float v = fminf(fmaxf(s[ni][r] * sc, -80.0f), 80.0f);   // NaN/Inf firewall
        s[ni][r] = v; mx = fmaxf(mx, v);
      }
#pragma unroll
      for (int m = 1; m < 16; m <<= 1) mx = fmaxf(mx, __shfl_xor(mx, m));
      float sum = 0.f;
      const int prow = mt * 16 + quad * 4 + r;
#pragma unroll
      for (int ni = 0; ni < 16; ++ni) {
        float e = exp2f(s[ni][r] - mx);
        sum += e;
        PsW[prow * 264 + ni * 16 + l16] = f2bf(e);
      }
#pragma unroll
      for (int m = 1; m < 16; m <<= 1) sum += __shfl_xor(sum, m);
      inv[mt][r] = 1.0f / sum;
    }
  }

  f32x4 c0[4] = {}, c1[4] = {};
#pragma unroll
  for (int kki = 0; kki < 8; ++kki) {
    short8 bfr[4];
#pragma unroll
    for (int ni = 0; ni < 4; ++ni)
      bfr[ni] = *(const short8*)(Vpb + (size_t)(ni * 16 + l16) * KPROJ + kki * 32 + quad * 8);
    short8 a0 = *(const short8*)(PsW + (l16) * 264 + kki * 32 + quad * 8);
    short8 a1 = *(const short8*)(PsW + (16 + l16) * 264 + kki * 32 + quad * 8);
#pragma unroll
    for (int ni = 0; ni < 4; ++ni) {
      c0[ni] = __builtin_amdgcn_mfma_f32_16x16x32_bf16(a0, bfr[ni], c0[ni], 0, 0, 0);
      c1[ni] = __builtin_amdgcn_mfma_f32_16x16x32_bf16(a1, bfr[ni], c1[ni], 0, 0, 0);
    }
  }
#pragma unroll
  for (int mt = 0; mt < 2; ++mt) {
    f32x4* c = mt ? c1 : c0;
#pragma unroll
    for (int ni = 0; ni < 4; ++ni)
#pragma unroll
      for (int r = 0; r < 4; ++r)
        Ctx[((size_t)b * T_SEQ + t0 + row0 + mt * 16 + quad * 4 + r) * DMODEL + h * DKH +
            ni * 16 + l16] = f2bf(c[ni][r] * inv[mt][r]);
  }
}

extern "C" void kernel_launch(void* const* d_in, const int* in_sizes, int n_in,
                              void* d_out, int out_size, void* d_ws, size_t ws_size,
                              hipStream_t stream) {
  (void)in_sizes; (void)n_in; (void)out_size; (void)ws_size;

  int* flag = (int*)d_ws;
  u16* base = (u16*)d_ws + 16;
  const size_t WSZ = 1048576;        // 1024*1024
  const size_t XSZ = 16777216;       // 4*4096*1024
  u16* wqT   = base + 0 * WSZ;
  u16* wkT   = base + 1 * WSZ;
  u16* wvT   = base + 2 * WSZ;
  u16* woT   = base + 3 * WSZ;
  u16* ekevT = base + 4 * WSZ;       // [ekT(256x4096); evT(256x4096)]
  u16* xT    = base + 6 * WSZ;       // (4, 1024, 4096)
  u16* xE    = xT + XSZ;             // (4, 512, 1024): rows 0-255 = Ek^T x, 256-511 = Ev^T x
  u16* Kp    = xE + 4 * 524288;      // (4, 256, 1024)
  u16* VpT   = Kp + 4 * 262144;      // (4, 1024, 256)
  u16* Q     = VpT + 4 * 262144;     // (4, 4096, 1024); also split-K partial buffer (32 MiB), then ctx
  u16* xbf   = (u16*)d_out;          // x bf16 scratch in d_out (dead before final gemm)
  float* xEp = (float*)Q;            // 16 blocks of 512*1024 fp32 partials (exactly Q's 32 MiB)

  sniff_dtype<<<1, 64, 0, stream>>>((const u16*)d_in[0], flag);
  convert_x<<<XSZ / 2048, 256, 0, stream>>>(d_in[0], xbf, flag, (int)XSZ);

  dim3 tb(32, 8);
  transpose_cvt<<<dim3(32, 32, 1), tb, 0, stream>>>(d_in[1], wqT, 1024, 1024, flag);
  transpose_cvt<<<dim3(32, 32, 1), tb, 0, stream>>>(d_in[2], wkT, 1024, 1024, flag);
  transpose_cvt<<<dim3(32, 32, 1), tb, 0, stream>>>(d_in[3], wvT, 1024, 1024, flag);
  transpose_cvt<<<dim3(32, 32, 1), tb, 0, stream>>>(d_in[6], woT, 1024, 1024, flag);
  transpose_cvt<<<dim3(8, 128, 1), tb, 0, stream>>>(d_in[4], ekevT, 4096, 256, flag);
  transpose_cvt<<<dim3(8, 128, 1), tb, 0, stream>>>(d_in[5], ekevT + KPROJ * T_SEQ, 4096, 256, flag);
  transpose_cvt<<<dim3(32, 128, 4), tb, 0, stream>>>(d_in[0], xT, 4096, 1024, flag);

  // xE[b] = [Ek;Ev]^T @ x[b], split-K x4: z = b*4+s, each K-chunk 1024
  gemm_bt<2><<<dim3(8, 4, 16), 256, 0, stream>>>(ekevT, xT, nullptr, xEp, flag,
                                                 512, 1024, 1024, 4096, 4096,
                                                 0, (size_t)DMODEL * T_SEQ, 0);
  reduce_splitk<<<dim3(256, 4), 256, 0, stream>>>(xEp, xE);

  // Kp[b] = xEk[b] @ Wk -> (256 x 1024)
  gemm_bt<0><<<dim3(8, 2, 4), 256, 0, stream>>>(xE, wkT, nullptr, Kp, flag,
                                                256, 1024, 1024, 1024, 1024, 524288, 0, 262144);
  // Vp^T[b] = Wv^T @ xEv[b]^T -> (1024 x 256)
  gemm_bt<0><<<dim3(2, 8, 4), 256, 0, stream>>>(wvT, xE + 262144, nullptr, VpT, flag,
                                                1024, 256, 1024, 1024, 1024, 0, 524288, 262144);
  // Q = x @ Wq -> (16384 x 1024); overwrites the (now dead) split-K partials
  gemm_bt<0><<<dim3(8, 128, 1), 256, 0, stream>>>(xbf, wqT, nullptr, Q, flag,
                                                  16384, 1024, 1024, 1024, 1024, 0, 0, 0);

  attn_fused<<<dim3(64, 64), 128, 0, stream>>>(Q, Kp, VpT, Q /*ctx in-place*/);

  // out = ctx @ Wo + bo (fp32 or bf16 per flag); xbf in d_out is dead now
  gemm_bt<1><<<dim3(8, 128, 1), 256, 0, stream>>>(Q, woT, d_in[7], d_out, flag,
                                                  16384, 1024, 1024, 1024, 1024, 0, 0, 0);
}

// Round 2
// 493.220 us; speedup vs baseline: 1.1513x; 1.0132x over previous
//
#include <hip/hip_runtime.h>

typedef unsigned short u16;
typedef __attribute__((ext_vector_type(8))) short short8;   // 8 bf16 = 4 VGPRs (MFMA A/B frag)
typedef __attribute__((ext_vector_type(4))) float f32x4;    // MFMA C/D frag

#define T_SEQ 4096
#define DMODEL 1024
#define NH 16
#define DKH 64
#define KPROJ 256

// ---------- bf16 helpers (bit-level, RNE) ----------
__device__ __forceinline__ u16 f2bf(float f) {
  union { float f; unsigned u; } v; v.f = f;
  unsigned r = v.u + 0x7FFFu + ((v.u >> 16) & 1u);
  return (u16)(r >> 16);
}
__device__ __forceinline__ float bf2f(u16 h) {
  union { unsigned u; float f; } v; v.u = ((unsigned)h) << 16; return v.f;
}
// pack 2 f32 -> 2 bf16 in one u32 (lo = a, hi = b); gfx950 HW RNE
__device__ __forceinline__ unsigned cvt_pk_bf16(float a, float b) {
  unsigned r;
  asm("v_cvt_pk_bf16_f32 %0, %1, %2" : "=v"(r) : "v"(a), "v"(b));
  return r;
}

// ---------- async global->LDS, 16B/lane; LDS base wave-uniform, lane i lands at +16*i ----------
__device__ __forceinline__ void gl2lds16(const u16* g, u16* l) {
  __builtin_amdgcn_global_load_lds(
      (const __attribute__((address_space(1))) unsigned int*)g,
      (__attribute__((address_space(3))) unsigned int*)(unsigned int)(unsigned long long)l,
      16, 0, 0);
}

// ---------- dtype sniffer: fp32 read as u16 pairs -> ~0.4% NaN/Inf bf16 patterns ----------
__global__ void sniff_dtype(const u16* __restrict__ x, int* __restrict__ flag) {
  int c = 0;
  for (int i = threadIdx.x; i < 8192; i += 64)
    if ((x[2 * i] & 0x7F80) == 0x7F80) c++;
#pragma unroll
  for (int m = 1; m < 64; m <<= 1) c += __shfl_xor(c, m);
  if (threadIdx.x == 0) *flag = (c > 0) ? 1 : 0;   // 1 = inputs are float32
}

// ---------- x -> bf16 row-major copy/downconvert ----------
__global__ void convert_x(const void* __restrict__ xin, u16* __restrict__ xout,
                          const int* __restrict__ flag, int n) {
  const int i = (blockIdx.x * 256 + threadIdx.x) * 8;
  if (i >= n) return;
  if (*flag) {
    const float* f = (const float*)xin + i;
    union { u16 s[8]; short8 v; } o;
#pragma unroll
    for (int j = 0; j < 8; ++j) o.s[j] = f2bf(f[j]);
    *(short8*)(xout + i) = o.v;
  } else {
    *(short8*)(xout + i) = *(const short8*)((const u16*)xin + i);
  }
}

// ---------- batched tiled transpose+convert: out[z][c][r] = bf16(in[z][r][c]) ----------
__global__ void transpose_cvt(const void* __restrict__ in, u16* __restrict__ out,
                              int R, int C, const int* __restrict__ flag) {
  __shared__ u16 tile[32][33];
  const bool f32 = (*flag != 0);
  const size_t zoff = (size_t)blockIdx.z * R * C;
  const int c0 = blockIdx.x * 32, r0 = blockIdx.y * 32;
  for (int i = threadIdx.y; i < 32; i += 8) {
    const size_t idx = zoff + (size_t)(r0 + i) * C + c0 + threadIdx.x;
    tile[i][threadIdx.x] = f32 ? f2bf(((const float*)in)[idx]) : ((const u16*)in)[idx];
  }
  __syncthreads();
  for (int i = threadIdx.y; i < 32; i += 8)
    out[zoff + (size_t)(c0 + i) * R + r0 + threadIdx.x] = tile[threadIdx.x][i];
}

// ---------- split-K reduce: xE[b][j] = bf16(sum_s P[(b*4+s)*stride + j]) ----------
__global__ void reduce_splitk(const float* __restrict__ P, u16* __restrict__ out) {
  const int b = blockIdx.y;
  const int j = (blockIdx.x * 256 + threadIdx.x) * 8;
  const float* p = P + (size_t)b * 4 * 524288 + j;
  float acc[8] = {};
#pragma unroll
  for (int s = 0; s < 4; ++s) {
    const float4 v0 = *(const float4*)(p + (size_t)s * 524288);
    const float4 v1 = *(const float4*)(p + (size_t)s * 524288 + 4);
    acc[0] += v0.x; acc[1] += v0.y; acc[2] += v0.z; acc[3] += v0.w;
    acc[4] += v1.x; acc[5] += v1.y; acc[6] += v1.z; acc[7] += v1.w;
  }
  union { u16 s[8]; short8 v; } o;
#pragma unroll
  for (int k = 0; k < 8; ++k) o.s[k] = f2bf(acc[k]);
  *(short8*)(out + (size_t)b * 524288 + j) = o.v;
}

// ---------- batched C = A(MxK') @ Bt(NxK')^T, 128x128 tile, BK=32, 4 waves ----------
// 2-phase double-buffered prefetch + XCD-aware bijective block swizzle.
// MODE 0: bf16 C; batch strides sA/sB/sC, ldA=ldB=K.
// MODE 1: + bias[n]; out dtype fp32/bf16 per *flag.
// MODE 2: split-K fp32 partials: z = b*4+s; kstart = s*K; P block z of M*N floats.
template <int MODE>
__global__ void __launch_bounds__(256) gemm_bt(const u16* __restrict__ A0, const u16* __restrict__ Bt0,
                                               const void* __restrict__ bias, void* __restrict__ Cv,
                                               const int* __restrict__ flag, int M, int N, int K,
                                               int ldA, int ldB, size_t sA, size_t sB, size_t sC) {
  __shared__ __align__(16) u16 As[2][128 * 32];
  __shared__ __align__(16) u16 Bs[2][128 * 32];

  const int gx = gridDim.x, gy = gridDim.y;
  const int gxy = gx * gy;
  const int nwg = gxy * gridDim.z;
  int lin = (blockIdx.z * gy + blockIdx.y) * gx + blockIdx.x;
  if ((nwg & 7) == 0) lin = (lin & 7) * (nwg >> 3) + (lin >> 3);
  const int bz = lin / gxy;
  const int rem = lin - bz * gxy;
  const int by = rem / gx;
  const int bx = rem - by * gx;

  const int z = bz;
  const int bb = (MODE == 2) ? (z >> 2) : z;
  const int kstart = (MODE == 2) ? ((z & 3) * K) : 0;
  const u16* A = A0 + (size_t)bb * sA;
  const u16* Bt = Bt0 + (size_t)bb * sB;
  const int tid = threadIdx.x;
  const int wid = tid >> 6, lane = tid & 63;
  const int wm = wid >> 1, wn = wid & 1;
  const int quad = lane >> 4, l16 = lane & 15;
  const int m0 = by * 128, n0 = bx * 128;
  const int srow = lane >> 2, scol = (lane & 3) * 8;

  const u16* Ag = A + (size_t)(m0 + srow) * ldA + scol + kstart;
  const u16* Bg = Bt + (size_t)(n0 + srow) * ldB + scol + kstart;

  f32x4 acc[4][4] = {};

  auto stage = [&](int buf, int k0) {
#pragma unroll
    for (int r = 0; r < 2; ++r) {
      const int rowb = r * 64 + wid * 16;               // wave-uniform LDS base
      gl2lds16(Ag + (size_t)rowb * ldA + k0, &As[buf][rowb * 32]);
      gl2lds16(Bg + (size_t)rowb * ldB + k0, &Bs[buf][rowb * 32]);
    }
  };

  const int nI = K >> 5;
  stage(0, 0);
  __syncthreads();
  int cur = 0;

  for (int t = 0; t < nI; ++t) {
    if (t + 1 < nI) stage(cur ^ 1, (t + 1) << 5);       // prefetch next tile
    short8 a[4], b[4];
#pragma unroll
    for (int mi = 0; mi < 4; ++mi)
      a[mi] = *(const short8*)(&As[cur][(wm * 64 + mi * 16 + l16) * 32 + quad * 8]);
#pragma unroll
    for (int ni = 0; ni < 4; ++ni)
      b[ni] = *(const short8*)(&Bs[cur][(wn * 64 + ni * 16 + l16) * 32 + quad * 8]);
#pragma unroll
    for (int mi = 0; mi < 4; ++mi)
#pragma unroll
      for (int ni = 0; ni < 4; ++ni)
        acc[mi][ni] = __builtin_amdgcn_mfma_f32_16x16x32_bf16(a[mi], b[ni], acc[mi][ni], 0, 0, 0);
    __syncthreads();                                    // drains vmcnt -> next buf ready
    cur ^= 1;
  }

  const bool f32out = (MODE == 1) && (*flag != 0);
  float* Pz = (MODE == 2) ? ((float*)Cv + (size_t)z * M * N) : nullptr;
#pragma unroll
  for (int mi = 0; mi < 4; ++mi) {
#pragma unroll
    for (int ni = 0; ni < 4; ++ni) {
      const int mloc = wm * 64 + mi * 16 + quad * 4;
      const int n = n0 + wn * 64 + ni * 16 + l16;
      float badd = 0.0f;
      if (MODE == 1)
        badd = f32out ? ((const float*)bias)[n] : bf2f(((const u16*)bias)[n]);
#pragma unroll
      for (int r = 0; r < 4; ++r) {
        if (MODE == 2) {
          Pz[(size_t)(m0 + mloc + r) * N + n] = acc[mi][ni][r];
        } else {
          const size_t oi = (size_t)bb * sC + (size_t)(m0 + mloc + r) * N + n;
          if (f32out) ((float*)Cv)[oi] = acc[mi][ni][r] + badd;
          else        ((u16*)Cv)[oi]  = f2bf(acc[mi][ni][r] + badd);
        }
      }
    }
  }
}

// ---------- fused scores+softmax+ctx ----------
// grid (T/32, B*H), ONE wave per block, 32 Q-rows.
// Swapped QK^T: s[mi][nt] = mfma(Kp_frag, Q_frag) -> C row = kp (quad*4+r), col = q (l16).
// Each lane owns 2 full P-rows (q = nt*16+l16); row reduce = local + 2 shuffles.
// P normalized in-register, packed via v_cvt_pk_bf16_f32, written as ds_write_b64.
// PV reads P rows back as A-frags (layout identical to previous version).
__global__ void __launch_bounds__(64, 2) attn_fused(const u16* Q, const u16* __restrict__ Kp,
                                                    const u16* __restrict__ VpT, u16* Ctx) {
  __shared__ __align__(16) u16 Ps[32 * 264];
  const int bh = blockIdx.y, b = bh >> 4, h = bh & 15;
  const int t0 = blockIdx.x * 32;
  const int lane = threadIdx.x;
  const int quad = lane >> 4, l16 = lane & 15;
  const u16* Qb = Q + ((size_t)b * T_SEQ + t0) * DMODEL + h * DKH;
  const u16* Kpb = Kp + (size_t)b * (KPROJ * DMODEL) + h * DKH;
  const u16* Vpb = VpT + (size_t)b * (DMODEL * KPROJ) + (size_t)(h * DKH) * KPROJ;

  f32x4 s[16][2] = {};
#pragma unroll
  for (int kk = 0; kk < 2; ++kk) {
    short8 kfr[16];
#pragma unroll
    for (int mi = 0; mi < 16; ++mi)
      kfr[mi] = *(const short8*)(Kpb + (size_t)(mi * 16 + l16) * DMODEL + kk * 32 + quad * 8);
    short8 q0 = *(const short8*)(Qb + (size_t)l16 * DMODEL + kk * 32 + quad * 8);
    short8 q1 = *(const short8*)(Qb + (size_t)(16 + l16) * DMODEL + kk * 32 + quad * 8);
    __builtin_amdgcn_s_setprio(1);
#pragma unroll
    for (int mi = 0; mi < 16; ++mi) {
      s[mi][0] = __builtin_amdgcn_mfma_f32_16x16x32_bf16(kfr[mi], q0, s[mi][0], 0, 0, 0);
      s[mi][1] = __builtin_amdgcn_mfma_f32_16x16x32_bf16(kfr[mi], q1, s[mi][1], 0, 0, 0);
    }
    __builtin_amdgcn_s_setprio(0);
  }

  // ---- in-register softmax (rows lane-local; only 8 shuffles total) ----
  const float sc = 0.125f * 1.44269504f;   // 1/sqrt(64) * log2(e)
  float mx0 = -3.0e38f, mx1 = -3.0e38f;
#pragma unroll
  for (int mi = 0; mi < 16; ++mi) {
#pragma unroll
    for (int r = 0; r < 4; ++r) {
      float v0 = fminf(fmaxf(s[mi][0][r] * sc, -80.0f), 80.0f);   // NaN/Inf firewall
      float v1 = fminf(fmaxf(s[mi][1][r] * sc, -80.0f), 80.0f);
      s[mi][0][r] = v0; s[mi][1][r] = v1;
      mx0 = fmaxf(mx0, v0); mx1 = fmaxf(mx1, v1);
    }
  }
  mx0 = fmaxf(mx0, __shfl_xor(mx0, 16)); mx0 = fmaxf(mx0, __shfl_xor(mx0, 32));
  mx1 = fmaxf(mx1, __shfl_xor(mx1, 16)); mx1 = fmaxf(mx1, __shfl_xor(mx1, 32));

  float sm0 = 0.0f, sm1 = 0.0f;
#pragma unroll
  for (int mi = 0; mi < 16; ++mi) {
#pragma unroll
    for (int r = 0; r < 4; ++r) {
      float e0 = exp2f(s[mi][0][r] - mx0);
      float e1 = exp2f(s[mi][1][r] - mx1);
      s[mi][0][r] = e0; s[mi][1][r] = e1;
      sm0 += e0; sm1 += e1;
    }
  }
  sm0 += __shfl_xor(sm0, 16); sm0 += __shfl_xor(sm0, 32);
  sm1 += __shfl_xor(sm1, 16); sm1 += __shfl_xor(sm1, 32);
  const float inv0 = 1.0f / sm0, inv1 = 1.0f / sm1;

  // ---- scale + pack + b64 write: P[q][kp], kp = mi*16 + quad*4 + r ----
#pragma unroll
  for (int mi = 0; mi < 16; ++mi) {
#pragma unroll
    for (int nt = 0; nt < 2; ++nt) {
      const float iv = nt ? inv1 : inv0;
      const unsigned lo = cvt_pk_bf16(s[mi][nt][0] * iv, s[mi][nt][1] * iv);
      const unsigned hi = cvt_pk_bf16(s[mi][nt][2] * iv, s[mi][nt][3] * iv);
      *(uint2*)(Ps + (nt * 16 + l16) * 264 + mi * 16 + quad * 4) = make_uint2(lo, hi);
    }
  }

  // ---- PV: ctx[q][d] = sum_k P[q][k] * VpT[d][k] ----
  f32x4 c0[4] = {}, c1[4] = {};
#pragma unroll
  for (int kki = 0; kki < 8; ++kki) {
    short8 bfr[4];
#pragma unroll
    for (int ni = 0; ni < 4; ++ni)
      bfr[ni] = *(const short8*)(Vpb + (size_t)(ni * 16 + l16) * KPROJ + kki * 32 + quad * 8);
    short8 a0 = *(const short8*)(Ps + (size_t)l16 * 264 + kki * 32 + quad * 8);
    short8 a1 = *(const short8*)(Ps + (size_t)(16 + l16) * 264 + kki * 32 + quad * 8);
    __builtin_amdgcn_s_setprio(1);
#pragma unroll
    for (int ni = 0; ni < 4; ++ni) {
      c0[ni] = __builtin_amdgcn_mfma_f32_16x16x32_bf16(a0, bfr[ni], c0[ni], 0, 0, 0);
      c1[ni] = __builtin_amdgcn_mfma_f32_16x16x32_bf16(a1, bfr[ni], c1[ni], 0, 0, 0);
    }
    __builtin_amdgcn_s_setprio(0);
  }

#pragma unroll
  for (int nt = 0; nt < 2; ++nt) {
    f32x4* c = nt ? c1 : c0;
#pragma unroll
    for (int ni = 0; ni < 4; ++ni)
#pragma unroll
      for (int r = 0; r < 4; ++r)
        Ctx[((size_t)b * T_SEQ + t0 + nt * 16 + quad * 4 + r) * DMODEL + h * DKH +
            ni * 16 + l16] = f2bf(c[ni][r]);
  }
}

extern "C" void kernel_launch(void* const* d_in, const int* in_sizes, int n_in,
                              void* d_out, int out_size, void* d_ws, size_t ws_size,
                              hipStream_t stream) {
  (void)in_sizes; (void)n_in; (void)out_size; (void)ws_size;

  int* flag = (int*)d_ws;
  u16* base = (u16*)d_ws + 16;
  const size_t WSZ = 1048576;        // 1024*1024
  const size_t XSZ = 16777216;       // 4*4096*1024
  u16* wqT   = base + 0 * WSZ;
  u16* wkT   = base + 1 * WSZ;
  u16* wvT   = base + 2 * WSZ;
  u16* woT   = base + 3 * WSZ;
  u16* ekevT = base + 4 * WSZ;       // [ekT(256x4096); evT(256x4096)]
  u16* xT    = base + 6 * WSZ;       // (4, 1024, 4096)
  u16* xE    = xT + XSZ;             // (4, 512, 1024): rows 0-255 = Ek^T x, 256-511 = Ev^T x
  u16* Kp    = xE + 4 * 524288;      // (4, 256, 1024)
  u16* VpT   = Kp + 4 * 262144;      // (4, 1024, 256)
  u16* Q     = VpT + 4 * 262144;     // (4, 4096, 1024); also split-K partial buffer (32 MiB), then ctx
  u16* xbf   = (u16*)d_out;          // x bf16 scratch in d_out (dead before final gemm)
  float* xEp = (float*)Q;            // 16 blocks of 512*1024 fp32 partials (exactly Q's 32 MiB)

  sniff_dtype<<<1, 64, 0, stream>>>((const u16*)d_in[0], flag);
  convert_x<<<XSZ / 2048, 256, 0, stream>>>(d_in[0], xbf, flag, (int)XSZ);

  dim3 tb(32, 8);
  transpose_cvt<<<dim3(32, 32, 1), tb, 0, stream>>>(d_in[1], wqT, 1024, 1024, flag);
  transpose_cvt<<<dim3(32, 32, 1), tb, 0, stream>>>(d_in[2], wkT, 1024, 1024, flag);
  transpose_cvt<<<dim3(32, 32, 1), tb, 0, stream>>>(d_in[3], wvT, 1024, 1024, flag);
  transpose_cvt<<<dim3(32, 32, 1), tb, 0, stream>>>(d_in[6], woT, 1024, 1024, flag);
  transpose_cvt<<<dim3(8, 128, 1), tb, 0, stream>>>(d_in[4], ekevT, 4096, 256, flag);
  transpose_cvt<<<dim3(8, 128, 1), tb, 0, stream>>>(d_in[5], ekevT + KPROJ * T_SEQ, 4096, 256, flag);
  transpose_cvt<<<dim3(32, 128, 4), tb, 0, stream>>>(d_in[0], xT, 4096, 1024, flag);

  // xE[b] = [Ek;Ev]^T @ x[b], split-K x4: z = b*4+s, each K-chunk 1024
  gemm_bt<2><<<dim3(8, 4, 16), 256, 0, stream>>>(ekevT, xT, nullptr, xEp, flag,
                                                 512, 1024, 1024, 4096, 4096,
                                                 0, (size_t)DMODEL * T_SEQ, 0);
  reduce_splitk<<<dim3(256, 4), 256, 0, stream>>>(xEp, xE);

  // Kp[b] = xEk[b] @ Wk -> (256 x 1024)
  gemm_bt<0><<<dim3(8, 2, 4), 256, 0, stream>>>(xE, wkT, nullptr, Kp, flag,
                                                256, 1024, 1024, 1024, 1024, 524288, 0, 262144);
  // Vp^T[b] = Wv^T @ xEv[b]^T -> (1024 x 256)
  gemm_bt<0><<<dim3(2, 8, 4), 256, 0, stream>>>(wvT, xE + 262144, nullptr, VpT, flag,
                                                1024, 256, 1024, 1024, 1024, 0, 524288, 262144);
  // Q = x @ Wq -> (16384 x 1024); overwrites the (now dead) split-K partials
  gemm_bt<0><<<dim3(8, 128, 1), 256, 0, stream>>>(xbf, wqT, nullptr, Q, flag,
                                                  16384, 1024, 1024, 1024, 1024, 0, 0, 0);

  attn_fused<<<dim3(128, 64), 64, 0, stream>>>(Q, Kp, VpT, Q /*ctx in-place*/);

  // out = ctx @ Wo + bo (fp32 or bf16 per flag); xbf in d_out is dead now
  gemm_bt<1><<<dim3(8, 128, 1), 256, 0, stream>>>(Q, woT, d_in[7], d_out, flag,
                                                  16384, 1024, 1024, 1024, 1024, 0, 0, 0);
}